// Round 8
// baseline (781.872 us; speedup 1.0000x reference)
//
#include <hip/hip_runtime.h>

// GraphSAGE encoder, restructured: aggregate AFTER linear maps.
//   N=50000, G=2000, E=800000, H=512, Z=64
// GEMM1: bf16 MFMA 256x256 tile, 8 waves (2x4 of 128x64), 3-ring LDS pipeline,
//        counted vmcnt(4), 2 sub-phases per K-iter with mid s_barrier
//        (fine ds_read || stage || MFMA interleave), setprio, XCD swizzle,
//        both-sides 16B-granule LDS swizzle ((row>>1)&3 XOR, conflict-free).
// agg1 / GEMM2 / agg2: all-bf16 intermediate dataflow, fp32 accumulation.

#define BN_EPS 1e-5f
#define GK 2000      // K of GEMM1
#define KP 2048      // padded K
#define NT1C 63      // ceil(2000/32) for cvt fallback path
#define NT1P 64      // 2048/32 for pure path
#define NT2 16       // 512/32

typedef __attribute__((ext_vector_type(8))) short bf16x8;
typedef __attribute__((ext_vector_type(4))) float f32x4;
typedef unsigned short u16x8 __attribute__((ext_vector_type(8)));

__device__ inline unsigned short f2bf(float f) {
    union { float f; unsigned u; } v; v.f = f;
    unsigned r = (v.u + 0x7fffu + ((v.u >> 16) & 1u)) >> 16;
    return (unsigned short)r;
}
__device__ inline float bf2f(unsigned short u) {
    union { unsigned u; float f; } v; v.u = ((unsigned)u) << 16;
    return v.f;
}

#define GLL16(gp, lp) __builtin_amdgcn_global_load_lds( \
    (const __attribute__((address_space(1))) void*)(gp), \
    (__attribute__((address_space(3))) void*)(lp), 16, 0, 0)

// ---------------- degree histogram ----------------
__global__ void count_kernel(const int* __restrict__ ei, int E, int* __restrict__ cnt) {
    int i = blockIdx.x * blockDim.x + threadIdx.x;
    if (i < E) atomicAdd(&cnt[ei[E + i]], 1);   // dst = ei[1][i]
}

// ---------------- exclusive scan over N counts (single block) ----------------
__global__ __launch_bounds__(1024) void scan_kernel(const int* __restrict__ cnt,
                                                    int* __restrict__ row_start, int n) {
    __shared__ int part[1024];
    int t = threadIdx.x;
    int chunk = (n + 1023) >> 10;
    int lo = t * chunk;
    int hi = lo + chunk; if (hi > n) hi = n;
    int s = 0;
    for (int i = lo; i < hi; ++i) s += cnt[i];
    part[t] = s;
    __syncthreads();
    for (int off = 1; off < 1024; off <<= 1) {
        int add = (t >= off) ? part[t - off] : 0;
        __syncthreads();
        part[t] += add;
        __syncthreads();
    }
    int run = (t == 0) ? 0 : part[t - 1];
    for (int i = lo; i < hi; ++i) { row_start[i] = run; run += cnt[i]; }
    if (t == 1023) row_start[n] = part[1023];
}

// ---------------- CSR fill (consumes cnt via atomicSub; cnt dead after) ---------
__global__ void fill_kernel(const int* __restrict__ ei, int E,
                            const int* __restrict__ row_start,
                            int* __restrict__ cnt, int* __restrict__ colidx) {
    int i = blockIdx.x * blockDim.x + threadIdx.x;
    if (i < E) {
        int d = ei[E + i];
        int p = atomicSub(&cnt[d], 1) - 1;
        colidx[row_start[d] + p] = ei[i];   // src
    }
}

// ---------------- x [M][2000] f32 -> xb [M][2048] bf16 (grid-stride) -------------
__global__ __launch_bounds__(256) void conv_kernel(const float* __restrict__ x,
                                                   unsigned short* __restrict__ xb,
                                                   int total8) {
    for (int idx = blockIdx.x * 256 + threadIdx.x; idx < total8;
         idx += gridDim.x * 256) {
        int row = idx >> 8;
        int k8  = idx & 255;   // group of 8; 250 valid, 6 pad
        unsigned short us[8];
        if (k8 < 250) {
            const float4* p = (const float4*)(x + (size_t)row * 2000 + k8 * 8);
            float4 v0 = p[0], v1 = p[1];
            us[0]=f2bf(v0.x); us[1]=f2bf(v0.y); us[2]=f2bf(v0.z); us[3]=f2bf(v0.w);
            us[4]=f2bf(v1.x); us[5]=f2bf(v1.y); us[6]=f2bf(v1.z); us[7]=f2bf(v1.w);
        } else {
#pragma unroll
            for (int j = 0; j < 8; ++j) us[j] = 0;
        }
        *(u16x8*)&xb[(size_t)row * 2048 + k8 * 8] = *(u16x8*)us;
    }
}

// ---------------- BT1[1024][2048] bf16 = [W1l|W1r]^T, zero-padded ----------------
__global__ __launch_bounds__(256) void prep_bt(const float* __restrict__ W1l,
                                               const float* __restrict__ W1r,
                                               unsigned short* __restrict__ BT) {
    int idx = blockIdx.x * 256 + threadIdx.x;
    int c  = idx >> 8;
    int k0 = (idx & 255) << 3;
    const float* W = (c < 512) ? (W1l + c) : (W1r + (c - 512));
    unsigned short us[8];
#pragma unroll
    for (int j = 0; j < 8; ++j) {
        int k = k0 + j;
        float v = (k < GK) ? W[(size_t)k * 512] : 0.0f;
        us[j] = f2bf(v);
    }
    *(u16x8*)&BT[(size_t)c * KP + k0] = *(u16x8*)us;
}

// ---------------- BT2[128][512] bf16 = [W2l|W2r]^T ----------------
__global__ __launch_bounds__(256) void prep_bt2(const float* __restrict__ W2l,
                                                const float* __restrict__ W2r,
                                                unsigned short* __restrict__ BT2) {
    int idx = blockIdx.x * 256 + threadIdx.x;
    int c  = idx >> 6;
    int k0 = (idx & 63) << 3;
    const float* W = (c < 64) ? (W2l + c) : (W2r + (c - 64));
    unsigned short us[8];
#pragma unroll
    for (int j = 0; j < 8; ++j) us[j] = f2bf(W[(size_t)(k0 + j) * 64]);
    *(u16x8*)&BT2[(size_t)c * 512 + k0] = *(u16x8*)us;
}

// ---------------- GEMM1: Y = xb(bf16) @ BT^T — 256x256, 3-ring, 2 sub-phases -----
// Per iter (ring slot rb): vmcnt(4) -> barrier -> [ph1: 8 ds_read (af m0-3 + bfr)
// + stage A(it+2) + 16 MFMA] -> mid barrier -> [ph2: 4 ds_read (af m4-7) +
// stage B(it+2) + 16 MFMA]. Staging still after the top barrier & targets rb+2,
// gll FIFO order unchanged -> vmcnt(4) semantics identical to round-5/6 kernel.
__global__ __launch_bounds__(512) void gemm1_256(
    const unsigned short* __restrict__ xb, int M,
    const unsigned short* __restrict__ BT,
    unsigned short* __restrict__ Y)
{
    __shared__ __align__(16) unsigned short As[3][8192];   // 256 rows x 32 k
    __shared__ __align__(16) unsigned short Bs[3][8192];   // 256 cols x 32 k

    const int t = threadIdx.x, wid = t >> 6, lane = t & 63;
    const int nbr = (M + 255) >> 8;
    const int nwg = nbr * 4;
    const int b   = blockIdx.x;
    int swz;
    if ((nwg & 7) == 0) swz = (b & 7) * (nwg >> 3) + (b >> 3);
    else swz = b;
    const int row0 = (swz >> 2) << 8;
    const int col0 = (swz & 3) << 8;

    // staging chunks c (16B each): c in {t, t+512}; row=c>>2, slot=c&3
    // source granule = slot ^ ((row>>1)&3) = (c&3) ^ ((c>>3)&3)
    const int c0 = t, c1 = t + 512;
    const int g0 = ((c0 & 3) ^ ((c0 >> 3) & 3)) << 3;   // elems
    const int g1 = ((c1 & 3) ^ ((c1 >> 3) & 3)) << 3;
    int ra0 = row0 + (c0 >> 2); if (ra0 >= M) ra0 = M - 1;
    int ra1 = row0 + (c1 >> 2); if (ra1 >= M) ra1 = M - 1;
    const unsigned short* aS0 = xb + (size_t)ra0 * KP + g0;
    const unsigned short* aS1 = xb + (size_t)ra1 * KP + g1;
    const unsigned short* bS0 = BT + (size_t)(col0 + (c0 >> 2)) * KP + g0;
    const unsigned short* bS1 = BT + (size_t)(col0 + (c1 >> 2)) * KP + g1;

    const int wr = wid >> 2, wc = wid & 3;   // 2 x 4 wave grid
    const int fr16 = lane & 15;
    const int gswr = ((lane >> 4) ^ ((fr16 >> 1) & 3)) << 4;   // read byte offset

    f32x4 acc[8][4];
#pragma unroll
    for (int m = 0; m < 8; ++m)
#pragma unroll
        for (int n = 0; n < 4; ++n) acc[m][n] = (f32x4)0.0f;

#define STG_A(kt, buf) do {                                        \
        unsigned short* ab_ = &As[buf][0];                         \
        GLL16(aS0 + (size_t)(kt) * 32, ab_ + c0 * 8);              \
        GLL16(aS1 + (size_t)(kt) * 32, ab_ + c1 * 8);              \
    } while (0)
#define STG_B(kt, buf) do {                                        \
        unsigned short* bb_ = &Bs[buf][0];                         \
        GLL16(bS0 + (size_t)(kt) * 32, bb_ + c0 * 8);              \
        GLL16(bS1 + (size_t)(kt) * 32, bb_ + c1 * 8);              \
    } while (0)

    // prologue: stage tiles 0 and 1 (8 loads/thread outstanding)
    STG_A(0, 0); STG_B(0, 0);
    STG_A(1, 1); STG_B(1, 1);

    int rb = 0;   // read buffer = it % 3
    for (int it = 0; it < NT1P; ++it) {
        // wait my 4 oldest loads (tile 'it'); tile it+1's 4 stay in flight.
        if (it == NT1P - 1) {
            asm volatile("s_waitcnt vmcnt(0)" ::: "memory");
        } else {
            asm volatile("s_waitcnt vmcnt(4)" ::: "memory");
        }
        __builtin_amdgcn_s_barrier();
        __builtin_amdgcn_sched_barrier(0);

        const char* Ab = (const char*)&As[rb][0];
        const char* Bb = (const char*)&Bs[rb][0];
        const int wb = (rb + 2 >= 3) ? rb - 1 : rb + 2;
        const bool do_stage = (it + 2 < NT1P);

        // ---- sub-phase 1: af[0..3] + bfr, stage A(it+2), MFMA m0..3 ----
        bf16x8 af0[4], bfr[4];
#pragma unroll
        for (int m = 0; m < 4; ++m)
            af0[m] = *(const bf16x8*)(Ab + ((wr * 128 + m * 16 + fr16) << 6) + gswr);
#pragma unroll
        for (int n = 0; n < 4; ++n)
            bfr[n] = *(const bf16x8*)(Bb + ((wc * 64 + n * 16 + fr16) << 6) + gswr);

        if (do_stage) STG_A(it + 2, wb);

        __builtin_amdgcn_s_setprio(1);
#pragma unroll
        for (int m = 0; m < 4; ++m)
#pragma unroll
            for (int n = 0; n < 4; ++n)
                acc[m][n] = __builtin_amdgcn_mfma_f32_16x16x32_bf16(
                    af0[m], bfr[n], acc[m][n], 0, 0, 0);
        __builtin_amdgcn_s_setprio(0);

        __builtin_amdgcn_s_barrier();        // mid barrier (scheduling stagger only)
        __builtin_amdgcn_sched_barrier(0);

        // ---- sub-phase 2: af[4..7], stage B(it+2), MFMA m4..7 ----
        bf16x8 af1[4];
#pragma unroll
        for (int m = 0; m < 4; ++m)
            af1[m] = *(const bf16x8*)(Ab + ((wr * 128 + (m + 4) * 16 + fr16) << 6) + gswr);

        if (do_stage) STG_B(it + 2, wb);

        __builtin_amdgcn_s_setprio(1);
#pragma unroll
        for (int m = 0; m < 4; ++m)
#pragma unroll
            for (int n = 0; n < 4; ++n)
                acc[m + 4][n] = __builtin_amdgcn_mfma_f32_16x16x32_bf16(
                    af1[m], bfr[n], acc[m + 4][n], 0, 0, 0);
        __builtin_amdgcn_s_setprio(0);

        rb = (rb == 2) ? 0 : rb + 1;
    }
#undef STG_A
#undef STG_B

    const int crow = (lane >> 4) << 2;
#pragma unroll
    for (int m = 0; m < 8; ++m) {
        int rbase = row0 + wr * 128 + m * 16 + crow;
#pragma unroll
        for (int r = 0; r < 4; ++r) {
            int row = rbase + r;
            if (row < M) {
                unsigned short* Yp = Y + (size_t)row * 1024 + col0 + wc * 64 + fr16;
#pragma unroll
                for (int n = 0; n < 4; ++n)
                    Yp[n * 16] = f2bf(acc[m][n][r]);
            }
        }
    }
}

// ---------------- GEMM1 fallback (in-kernel f32->bf16, 128^2) ----------------
__global__ __launch_bounds__(256) void gemm1_cvt(
    const float* __restrict__ A, int M,
    const unsigned short* __restrict__ BT,
    unsigned short* __restrict__ Y)
{
    __shared__ __align__(16) unsigned short As[128][32];
    __shared__ __align__(16) unsigned short Bs[2][128][32];

    const int t    = threadIdx.x;
    const int wid  = t >> 6;
    const int lane = t & 63;
    const int nby = (M + 127) >> 7;
    const int b   = blockIdx.x;
    const int swz = (b & 7) * nby + (b >> 3);
    const int row0 = (swz >> 3) << 7;
    const int col0 = (swz & 7) << 7;

    const int ar  = t >> 1;
    const int akq = (t & 1) << 4;
    int garow = row0 + ar; if (garow >= M) garow = M - 1;
    const float* aptr = A + (size_t)garow * GK + akq;

    const int i0 = wid * 64 + lane;
    const unsigned short* bptr0 = BT + ((size_t)(col0 + (i0 >> 2)) * KP + ((i0 & 3) << 3));
    const unsigned short* bptr1 = bptr0 + (size_t)64 * KP;

    const int wr   = wid >> 1, wc = wid & 1;
    const int fr16 = lane & 15;
    const int kb8  = (lane >> 4) << 3;

    f32x4 acc[4][4];
#pragma unroll
    for (int m = 0; m < 4; ++m)
#pragma unroll
        for (int n = 0; n < 4; ++n) acc[m][n] = (f32x4)0.0f;

    GLL16(bptr0, &Bs[0][wid * 16][0]);
    GLL16(bptr1, &Bs[0][64 + wid * 16][0]);

    float frg[16];
    {
        const float4* p = (const float4*)aptr;
        float4 v0 = p[0], v1 = p[1], v2 = p[2], v3 = p[3];
        frg[0]=v0.x; frg[1]=v0.y; frg[2]=v0.z;  frg[3]=v0.w;
        frg[4]=v1.x; frg[5]=v1.y; frg[6]=v1.z;  frg[7]=v1.w;
        frg[8]=v2.x; frg[9]=v2.y; frg[10]=v2.z; frg[11]=v2.w;
        frg[12]=v3.x;frg[13]=v3.y;frg[14]=v3.z; frg[15]=v3.w;
    }

    int cur = 0;
    for (int it = 0; it < NT1C; ++it) {
        {
            unsigned short us[16];
#pragma unroll
            for (int j = 0; j < 16; ++j) us[j] = f2bf(frg[j]);
            *(u16x8*)&As[ar][akq]     = *(u16x8*)&us[0];
            *(u16x8*)&As[ar][akq + 8] = *(u16x8*)&us[8];
        }
        __syncthreads();

        if (it + 1 < NT1C) {
            int kb = (it + 1) * 32 + akq;
            if (kb < GK) {
                const float4* p = (const float4*)(aptr + (size_t)(it + 1) * 32);
                float4 v0 = p[0], v1 = p[1], v2 = p[2], v3 = p[3];
                frg[0]=v0.x; frg[1]=v0.y; frg[2]=v0.z;  frg[3]=v0.w;
                frg[4]=v1.x; frg[5]=v1.y; frg[6]=v1.z;  frg[7]=v1.w;
                frg[8]=v2.x; frg[9]=v2.y; frg[10]=v2.z; frg[11]=v2.w;
                frg[12]=v3.x;frg[13]=v3.y;frg[14]=v3.z; frg[15]=v3.w;
            } else {
#pragma unroll
                for (int j = 0; j < 16; ++j) frg[j] = 0.0f;
            }
            const unsigned short* bp = bptr0 + (size_t)(it + 1) * 32;
            GLL16(bp,                   &Bs[cur ^ 1][wid * 16][0]);
            GLL16(bp + (size_t)64 * KP, &Bs[cur ^ 1][64 + wid * 16][0]);
        }

        bf16x8 af[4], bfr[4];
#pragma unroll
        for (int m = 0; m < 4; ++m)
            af[m] = *(const bf16x8*)&As[wr * 64 + m * 16 + fr16][kb8];
#pragma unroll
        for (int n = 0; n < 4; ++n)
            bfr[n] = *(const bf16x8*)&Bs[cur][wc * 64 + n * 16 + fr16][kb8];
#pragma unroll
        for (int m = 0; m < 4; ++m)
#pragma unroll
            for (int n = 0; n < 4; ++n)
                acc[m][n] = __builtin_amdgcn_mfma_f32_16x16x32_bf16(
                    af[m], bfr[n], acc[m][n], 0, 0, 0);

        __syncthreads();
        cur ^= 1;
    }

    const int crow = (lane >> 4) << 2;
#pragma unroll
    for (int m = 0; m < 4; ++m) {
        int rbase = row0 + wr * 64 + m * 16 + crow;
#pragma unroll
        for (int r = 0; r < 4; ++r) {
            int row = rbase + r;
            if (row < M) {
                unsigned short* Yp = Y + (size_t)row * 1024 + col0 + wc * 64 + fr16;
#pragma unroll
                for (int n = 0; n < 4; ++n)
                    Yp[n * 16] = f2bf(acc[m][n][r]);
            }
        }
    }
}

// ---------------- agg1: mean-gather(Yl) + b1 + self(Yr) + BN + ReLU -> h (bf16) ----
__global__ __launch_bounds__(256) void agg1_kernel(
    const unsigned short* __restrict__ Y, unsigned short* __restrict__ Hh,
    const int* __restrict__ row_start, const int* __restrict__ colidx,
    const float* __restrict__ b1, const float* __restrict__ gamma,
    const float* __restrict__ beta, const float* __restrict__ mean,
    const float* __restrict__ var, int n)
{
    int wid  = (blockIdx.x * blockDim.x + threadIdx.x) >> 6;
    int lane = threadIdx.x & 63;
    if (wid >= n) return;
    int c0 = lane * 8;
    float sc[8], sh[8], bb[8];
#pragma unroll
    for (int j = 0; j < 8; ++j) {
        int c = c0 + j;
        sc[j] = gamma[c] * rsqrtf(var[c] + BN_EPS);
        sh[j] = beta[c] - mean[c] * sc[j];
        bb[j] = b1[c];
    }
    int s0 = row_start[wid], s1 = row_start[wid + 1];
    float acc[8] = {0, 0, 0, 0, 0, 0, 0, 0};
    for (int i = s0; i < s1; ++i) {
        int src = colidx[i];
        u16x8 v = *(const u16x8*)&Y[(size_t)src * 1024 + c0];
#pragma unroll
        for (int j = 0; j < 8; ++j) acc[j] += bf2f(v[j]);
    }
    float inv = 1.0f / fmaxf((float)(s1 - s0), 1.0f);
    u16x8 sv = *(const u16x8*)&Y[(size_t)wid * 1024 + 512 + c0];
    unsigned short o[8];
#pragma unroll
    for (int j = 0; j < 8; ++j) {
        float pre = acc[j] * inv + bb[j] + bf2f(sv[j]);
        float h = pre * sc[j] + sh[j];
        o[j] = f2bf(fmaxf(h, 0.0f));
    }
    *(u16x8*)&Hh[(size_t)wid * 512 + c0] = *(u16x8*)o;
}

// ---------------- GEMM2: U[M x 128](bf16) = h[M x 512](bf16) @ BT2^T ------------
__global__ __launch_bounds__(256) void gemm2_bf16(
    const unsigned short* __restrict__ Hh, int M,
    const unsigned short* __restrict__ BT2,
    unsigned short* __restrict__ U)
{
    __shared__ __align__(16) unsigned short As[2][128][32];
    __shared__ __align__(16) unsigned short Bs[2][128][32];

    const int t    = threadIdx.x;
    const int wid  = t >> 6;
    const int lane = t & 63;
    const int row0 = blockIdx.x << 7;

    const int c_lo = wid * 64 + lane;
    const int c_hi = c_lo + 256;
    const int s_lo = ((c_lo & 3) ^ ((c_lo >> 3) & 3)) << 3;   // src granule (elems)
    const int s_hi = ((c_hi & 3) ^ ((c_hi >> 3) & 3)) << 3;
    int ra = row0 + (c_lo >> 2); if (ra >= M) ra = M - 1;
    int rbw = row0 + (c_hi >> 2); if (rbw >= M) rbw = M - 1;
    const unsigned short* aSrc0 = Hh + (size_t)ra * 512 + s_lo;
    const unsigned short* aSrc1 = Hh + (size_t)rbw * 512 + s_hi;
    const unsigned short* bSrc0 = BT2 + (size_t)(c_lo >> 2) * 512 + s_lo;
    const unsigned short* bSrc1 = BT2 + (size_t)(c_hi >> 2) * 512 + s_hi;

    const int wr   = wid >> 1, wc = wid & 1;
    const int fr16 = lane & 15;
    const int gsw2 = ((lane >> 4) ^ ((fr16 >> 1) & 3)) << 4;  // read byte offset

    f32x4 acc[4][4];
#pragma unroll
    for (int m = 0; m < 4; ++m)
#pragma unroll
        for (int n = 0; n < 4; ++n) acc[m][n] = (f32x4)0.0f;

#define STAGE2(kt, buf) do {                                                  \
        int ko = (kt) * 32;                                                   \
        GLL16(aSrc0 + ko, (unsigned short*)&As[buf][0][0] + (size_t)c_lo * 8);  \
        GLL16(aSrc1 + ko, (unsigned short*)&As[buf][0][0] + (size_t)c_hi * 8);  \
        GLL16(bSrc0 + ko, (unsigned short*)&Bs[buf][0][0] + (size_t)c_lo * 8);  \
        GLL16(bSrc1 + ko, (unsigned short*)&Bs[buf][0][0] + (size_t)c_hi * 8);  \
    } while (0)

    STAGE2(0, 0);
    int cur = 0;
    for (int it = 0; it < NT2; ++it) {
        __syncthreads();
        if (it + 1 < NT2) STAGE2(it + 1, cur ^ 1);

        const char* Ab = (const char*)&As[cur][0][0];
        const char* Bb = (const char*)&Bs[cur][0][0];
        bf16x8 af[4], bfr[4];
#pragma unroll
        for (int m = 0; m < 4; ++m)
            af[m] = *(const bf16x8*)(Ab + ((wr * 64 + m * 16 + fr16) << 6) + gsw2);
#pragma unroll
        for (int n = 0; n < 4; ++n)
            bfr[n] = *(const bf16x8*)(Bb + ((wc * 64 + n * 16 + fr16) << 6) + gsw2);
#pragma unroll
        for (int m = 0; m < 4; ++m)
#pragma unroll
            for (int n = 0; n < 4; ++n)
                acc[m][n] = __builtin_amdgcn_mfma_f32_16x16x32_bf16(
                    af[m], bfr[n], acc[m][n], 0, 0, 0);
        cur ^= 1;
    }
#undef STAGE2

    const int crow = (lane >> 4) << 2;
#pragma unroll
    for (int m = 0; m < 4; ++m) {
        int rbase = row0 + wr * 64 + m * 16 + crow;
#pragma unroll
        for (int r = 0; r < 4; ++r) {
            int row = rbase + r;
            if (row < M) {
                unsigned short* Up = U + (size_t)row * 128 + wc * 64 + fr16;
#pragma unroll
                for (int n = 0; n < 4; ++n)
                    Up[n * 16] = f2bf(acc[m][n][r]);
            }
        }
    }
}

// ---------------- agg2: mean-gather(Ul) + b2 + self(Ur) -> out (f32) ----------------
__global__ __launch_bounds__(256) void agg2_kernel(
    const unsigned short* __restrict__ U,
    const int* __restrict__ row_start, const int* __restrict__ colidx,
    const float* __restrict__ b2, float* __restrict__ out, int n)
{
    int wid  = (blockIdx.x * blockDim.x + threadIdx.x) >> 6;
    int lane = threadIdx.x & 63;
    if (wid >= n) return;
    int s0 = row_start[wid], s1 = row_start[wid + 1];
    float acc = 0.f;
    for (int i = s0; i < s1; ++i) {
        int src = colidx[i];
        acc += bf2f(U[(size_t)src * 128 + lane]);
    }
    float inv = 1.0f / fmaxf((float)(s1 - s0), 1.0f);
    float z = acc * inv + b2[lane] + bf2f(U[(size_t)wid * 128 + 64 + lane]);
    out[(size_t)wid * 64 + lane] = z;
}

extern "C" void kernel_launch(void* const* d_in, const int* in_sizes, int n_in,
                              void* d_out, int out_size, void* d_ws, size_t ws_size,
                              hipStream_t stream) {
    const float* x     = (const float*)d_in[0];
    const int*   ei    = (const int*)d_in[1];
    const float* W1l   = (const float*)d_in[2];
    const float* b1    = (const float*)d_in[3];
    const float* W1r   = (const float*)d_in[4];
    const float* gamma = (const float*)d_in[5];
    const float* beta  = (const float*)d_in[6];
    const float* mean  = (const float*)d_in[7];
    const float* var   = (const float*)d_in[8];
    const float* W2l   = (const float*)d_in[9];
    const float* b2    = (const float*)d_in[10];
    const float* W2r   = (const float*)d_in[11];
    float* out = (float*)d_out;

    const int N = in_sizes[0] / 2000;   // 50000
    const int E = in_sizes[1] / 2;      // 800000
    const int nby = (N + 127) / 128;

    char* ws = (char*)d_ws;

    // Primary layout: xb | Y | BT | BT2 | cnt | row_start | colidx
    //   (Hh aliases xb after gemm1; U aliases Y after agg1)
    size_t need = (size_t)N * KP * 2 + (size_t)N * 1024 * 2
                + (size_t)1024 * KP * 2 + (size_t)128 * 512 * 2
                + ((size_t)2 * N + 8 + (size_t)E) * 4;

    if (ws_size >= need) {
        unsigned short* xb  = (unsigned short*)ws;                 // N*2048 bf16
        unsigned short* Y   = xb + (size_t)N * KP;                 // N*1024 bf16
        unsigned short* BT  = Y + (size_t)N * 1024;                // 1024*2048 bf16
        unsigned short* BT2 = BT + (size_t)1024 * KP;              // 128*512 bf16
        int* cnt       = (int*)(BT2 + (size_t)128 * 512);
        int* row_start = cnt + N;
        int* colidx    = row_start + N + 4;                        // E
        unsigned short* Hh = xb;   // alias: xb dead after gemm1
        unsigned short* U  = Y;    // alias: Y dead after agg1

        hipMemsetAsync(cnt, 0, (size_t)N * sizeof(int), stream);

        prep_bt<<<1024, 256, 0, stream>>>(W1l, W1r, BT);
        prep_bt2<<<32, 256, 0, stream>>>(W2l, W2r, BT2);
        conv_kernel<<<2048, 256, 0, stream>>>(x, xb, N * 256);

        int eb = (E + 255) / 256;
        count_kernel<<<eb, 256, 0, stream>>>(ei, E, cnt);
        scan_kernel<<<1, 1024, 0, stream>>>(cnt, row_start, N);
        fill_kernel<<<eb, 256, 0, stream>>>(ei, E, row_start, cnt, colidx);

        int nbr = (N + 255) / 256;
        gemm1_256<<<nbr * 4, 512, 0, stream>>>(xb, N, BT, Y);
        agg1_kernel<<<(N + 3) / 4, 256, 0, stream>>>(
            Y, Hh, row_start, colidx, b1, gamma, beta, mean, var, N);
        gemm2_bf16<<<nby, 256, 0, stream>>>(Hh, N, BT2, U);
        agg2_kernel<<<(N + 3) / 4, 256, 0, stream>>>(
            U, row_start, colidx, b2, out, N);
    } else {
        // Fallback layout and kernels (128^2 cvt GEMM1)
        unsigned short* Y   = (unsigned short*)ws;                 // N*1024 bf16
        unsigned short* Hh  = Y + (size_t)N * 1024;                // N*512 bf16
        unsigned short* U   = Hh + (size_t)N * 512;                // N*128 bf16
        unsigned short* BT  = U + (size_t)N * 128;                 // 1024*2048 bf16
        unsigned short* BT2 = BT + (size_t)1024 * KP;              // 128*512 bf16
        int* cnt       = (int*)(BT2 + (size_t)128 * 512);
        int* row_start = cnt + N;
        int* colidx    = row_start + N + 4;

        hipMemsetAsync(cnt, 0, (size_t)N * sizeof(int), stream);

        prep_bt<<<1024, 256, 0, stream>>>(W1l, W1r, BT);
        prep_bt2<<<32, 256, 0, stream>>>(W2l, W2r, BT2);

        int eb = (E + 255) / 256;
        count_kernel<<<eb, 256, 0, stream>>>(ei, E, cnt);
        scan_kernel<<<1, 1024, 0, stream>>>(cnt, row_start, N);
        fill_kernel<<<eb, 256, 0, stream>>>(ei, E, row_start, cnt, colidx);

        gemm1_cvt<<<8 * nby, 256, 0, stream>>>(x, N, BT, Y);
        agg1_kernel<<<(N + 3) / 4, 256, 0, stream>>>(
            Y, Hh, row_start, colidx, b1, gamma, beta, mean, var, N);
        gemm2_bf16<<<nby, 256, 0, stream>>>(Hh, N, BT2, U);
        agg2_kernel<<<(N + 3) / 4, 256, 0, stream>>>(
            U, row_start, colidx, b2, out, N);
    }
}

// Round 9
// 701.235 us; speedup vs baseline: 1.1150x; 1.1150x over previous
//
#include <hip/hip_runtime.h>

// GraphSAGE encoder, restructured: aggregate AFTER linear maps; BN folded into W1.
//   N=50000, G=2000, E=800000, H=512, Z=64
// GEMM1: round-7 proven kernel (256x256, 3-ring, vmcnt(4), 1 barrier/iter,
//        conflict-free (row>>1)&3 granule swizzle, XCD swizzle, setprio).
// prep_fused: conv + BT1(BN-folded) + BT2 + b1' + degree-count in ONE launch
//        (atomic-bound count overlaps BW-bound conv; fewer launches).
// agg1: gather + b1' + self + ReLU (BN pre-folded), 2x edge unroll.

#define BN_EPS 1e-5f
#define GK 2000      // K of GEMM1
#define KP 2048      // padded K
#define NT1C 63      // ceil(2000/32) for cvt fallback path
#define NT1P 64      // 2048/32 for pure path
#define NT2 16       // 512/32

typedef __attribute__((ext_vector_type(8))) short bf16x8;
typedef __attribute__((ext_vector_type(4))) float f32x4;
typedef unsigned short u16x8 __attribute__((ext_vector_type(8)));

__device__ inline unsigned short f2bf(float f) {
    union { float f; unsigned u; } v; v.f = f;
    unsigned r = (v.u + 0x7fffu + ((v.u >> 16) & 1u)) >> 16;
    return (unsigned short)r;
}
__device__ inline float bf2f(unsigned short u) {
    union { unsigned u; float f; } v; v.u = ((unsigned)u) << 16;
    return v.f;
}

#define GLL16(gp, lp) __builtin_amdgcn_global_load_lds( \
    (const __attribute__((address_space(1))) void*)(gp), \
    (__attribute__((address_space(3))) void*)(lp), 16, 0, 0)

// ---------------- fused prep: conv | BT1 (BN-folded) | BT2 | b1' | count --------
// blocks [0,2048): conv grid-stride; [2048,3072): BT1; [3072,3104): BT2;
// block 3104: b1'; [3105,4096): degree histogram grid-stride.
__global__ __launch_bounds__(256) void prep_fused(
    const float* __restrict__ x, unsigned short* __restrict__ xb,
    const float* __restrict__ W1l, const float* __restrict__ W1r,
    const float* __restrict__ gamma, const float* __restrict__ beta,
    const float* __restrict__ mean, const float* __restrict__ var,
    const float* __restrict__ b1, unsigned short* __restrict__ BT,
    const float* __restrict__ W2l, const float* __restrict__ W2r,
    unsigned short* __restrict__ BT2, float* __restrict__ b1p,
    const int* __restrict__ ei, int* __restrict__ cnt, int N, int E)
{
    const int bb = blockIdx.x;
    if (bb < 2048) {
        // ---- conv: x [N][2000] f32 -> xb [N][2048] bf16 (zero-padded) ----
        const int total8 = N * 256;
        for (int idx = bb * 256 + threadIdx.x; idx < total8; idx += 2048 * 256) {
            int row = idx >> 8;
            int k8  = idx & 255;
            unsigned short us[8];
            if (k8 < 250) {
                const float4* p = (const float4*)(x + (size_t)row * 2000 + k8 * 8);
                float4 v0 = p[0], v1 = p[1];
                us[0]=f2bf(v0.x); us[1]=f2bf(v0.y); us[2]=f2bf(v0.z); us[3]=f2bf(v0.w);
                us[4]=f2bf(v1.x); us[5]=f2bf(v1.y); us[6]=f2bf(v1.z); us[7]=f2bf(v1.w);
            } else {
#pragma unroll
                for (int j = 0; j < 8; ++j) us[j] = 0;
            }
            *(u16x8*)&xb[(size_t)row * 2048 + k8 * 8] = *(u16x8*)us;
        }
    } else if (bb < 3072) {
        // ---- BT1[1024][2048] = ([W1l|W1r]*diag(sc))^T, zero-padded ----
        int idx = (bb - 2048) * 256 + threadIdx.x;
        int c  = idx >> 8;
        int k0 = (idx & 255) << 3;
        int cc = (c < 512) ? c : c - 512;
        float scv = gamma[cc] * rsqrtf(var[cc] + BN_EPS);
        const float* W = (c < 512) ? (W1l + cc) : (W1r + cc);
        unsigned short us[8];
#pragma unroll
        for (int j = 0; j < 8; ++j) {
            int k = k0 + j;
            float v = (k < GK) ? W[(size_t)k * 512] * scv : 0.0f;
            us[j] = f2bf(v);
        }
        *(u16x8*)&BT[(size_t)c * KP + k0] = *(u16x8*)us;
    } else if (bb < 3104) {
        // ---- BT2[128][512] = [W2l|W2r]^T ----
        int idx = (bb - 3072) * 256 + threadIdx.x;
        int c  = idx >> 6;
        int k0 = (idx & 63) << 3;
        const float* W = (c < 64) ? (W2l + c) : (W2r + (c - 64));
        unsigned short us[8];
#pragma unroll
        for (int j = 0; j < 8; ++j) us[j] = f2bf(W[(size_t)(k0 + j) * 64]);
        *(u16x8*)&BT2[(size_t)c * 512 + k0] = *(u16x8*)us;
    } else if (bb == 3104) {
        // ---- b1'[512] = b1*sc + (beta - mean*sc) ----
#pragma unroll
        for (int h = 0; h < 2; ++h) {
            int c = threadIdx.x + h * 256;
            float scv = gamma[c] * rsqrtf(var[c] + BN_EPS);
            b1p[c] = b1[c] * scv + (beta[c] - mean[c] * scv);
        }
    } else {
        // ---- degree histogram (dst = ei[1][i]) ----
        for (int i = (bb - 3105) * 256 + threadIdx.x; i < E; i += 991 * 256)
            atomicAdd(&cnt[ei[E + i]], 1);
    }
}

// ---------------- exclusive scan over N counts (single block) ----------------
__global__ __launch_bounds__(1024) void scan_kernel(const int* __restrict__ cnt,
                                                    int* __restrict__ row_start, int n) {
    __shared__ int part[1024];
    int t = threadIdx.x;
    int chunk = (n + 1023) >> 10;
    int lo = t * chunk;
    int hi = lo + chunk; if (hi > n) hi = n;
    int s = 0;
    for (int i = lo; i < hi; ++i) s += cnt[i];
    part[t] = s;
    __syncthreads();
    for (int off = 1; off < 1024; off <<= 1) {
        int add = (t >= off) ? part[t - off] : 0;
        __syncthreads();
        part[t] += add;
        __syncthreads();
    }
    int run = (t == 0) ? 0 : part[t - 1];
    for (int i = lo; i < hi; ++i) { row_start[i] = run; run += cnt[i]; }
    if (t == 1023) row_start[n] = part[1023];
}

// ---------------- CSR fill (consumes cnt via atomicSub; cnt dead after) ---------
__global__ void fill_kernel(const int* __restrict__ ei, int E,
                            const int* __restrict__ row_start,
                            int* __restrict__ cnt, int* __restrict__ colidx) {
    int i = blockIdx.x * blockDim.x + threadIdx.x;
    if (i < E) {
        int d = ei[E + i];
        int p = atomicSub(&cnt[d], 1) - 1;
        colidx[row_start[d] + p] = ei[i];   // src
    }
}

// ---------------- GEMM1 (round-7 proven): 256x256, 3-ring, counted vmcnt --------
__global__ __launch_bounds__(512) void gemm1_256(
    const unsigned short* __restrict__ xb, int M,
    const unsigned short* __restrict__ BT,
    unsigned short* __restrict__ Y)
{
    __shared__ __align__(16) unsigned short As[3][8192];   // 256 rows x 32 k
    __shared__ __align__(16) unsigned short Bs[3][8192];   // 256 cols x 32 k

    const int t = threadIdx.x, wid = t >> 6, lane = t & 63;
    const int nbr = (M + 255) >> 8;
    const int nwg = nbr * 4;
    const int b   = blockIdx.x;
    int swz;
    if ((nwg & 7) == 0) swz = (b & 7) * (nwg >> 3) + (b >> 3);
    else swz = b;
    const int row0 = (swz >> 2) << 8;
    const int col0 = (swz & 3) << 8;

    // staging chunks c (16B each): c in {t, t+512}; row=c>>2, slot=c&3
    // source granule = slot ^ ((row>>1)&3) = (c&3) ^ ((c>>3)&3)
    const int c0 = t, c1 = t + 512;
    const int g0 = ((c0 & 3) ^ ((c0 >> 3) & 3)) << 3;   // elems
    const int g1 = ((c1 & 3) ^ ((c1 >> 3) & 3)) << 3;
    int ra0 = row0 + (c0 >> 2); if (ra0 >= M) ra0 = M - 1;
    int ra1 = row0 + (c1 >> 2); if (ra1 >= M) ra1 = M - 1;
    const unsigned short* aS0 = xb + (size_t)ra0 * KP + g0;
    const unsigned short* aS1 = xb + (size_t)ra1 * KP + g1;
    const unsigned short* bS0 = BT + (size_t)(col0 + (c0 >> 2)) * KP + g0;
    const unsigned short* bS1 = BT + (size_t)(col0 + (c1 >> 2)) * KP + g1;

    const int wr = wid >> 2, wc = wid & 3;   // 2 x 4 wave grid
    const int fr16 = lane & 15;
    const int gswr = ((lane >> 4) ^ ((fr16 >> 1) & 3)) << 4;   // read byte offset

    f32x4 acc[8][4];
#pragma unroll
    for (int m = 0; m < 8; ++m)
#pragma unroll
        for (int n = 0; n < 4; ++n) acc[m][n] = (f32x4)0.0f;

#define STG(kt, buf) do {                                          \
        unsigned short* ab_ = &As[buf][0];                         \
        unsigned short* bb_ = &Bs[buf][0];                         \
        GLL16(aS0 + (size_t)(kt) * 32, ab_ + c0 * 8);              \
        GLL16(aS1 + (size_t)(kt) * 32, ab_ + c1 * 8);              \
        GLL16(bS0 + (size_t)(kt) * 32, bb_ + c0 * 8);              \
        GLL16(bS1 + (size_t)(kt) * 32, bb_ + c1 * 8);              \
    } while (0)

    // prologue: stage tiles 0 and 1 (8 loads/thread outstanding)
    STG(0, 0);
    STG(1, 1);

    int rb = 0;   // read buffer = it % 3
    for (int it = 0; it < NT1P; ++it) {
        if (it == NT1P - 1) {
            asm volatile("s_waitcnt vmcnt(0)" ::: "memory");
        } else {
            asm volatile("s_waitcnt vmcnt(4)" ::: "memory");
        }
        __builtin_amdgcn_s_barrier();
        __builtin_amdgcn_sched_barrier(0);

        const char* Ab = (const char*)&As[rb][0];
        const char* Bb = (const char*)&Bs[rb][0];
        bf16x8 af[8], bfr[4];
#pragma unroll
        for (int m = 0; m < 8; ++m)
            af[m] = *(const bf16x8*)(Ab + ((wr * 128 + m * 16 + fr16) << 6) + gswr);
#pragma unroll
        for (int n = 0; n < 4; ++n)
            bfr[n] = *(const bf16x8*)(Bb + ((wc * 64 + n * 16 + fr16) << 6) + gswr);

        if (it + 2 < NT1P) {
            int wb = rb + 2; if (wb >= 3) wb -= 3;
            STG(it + 2, wb);
        }

        __builtin_amdgcn_s_setprio(1);
#pragma unroll
        for (int m = 0; m < 8; ++m)
#pragma unroll
            for (int n = 0; n < 4; ++n)
                acc[m][n] = __builtin_amdgcn_mfma_f32_16x16x32_bf16(
                    af[m], bfr[n], acc[m][n], 0, 0, 0);
        __builtin_amdgcn_s_setprio(0);

        rb = (rb == 2) ? 0 : rb + 1;
    }
#undef STG

    const int crow = (lane >> 4) << 2;
#pragma unroll
    for (int m = 0; m < 8; ++m) {
        int rbase = row0 + wr * 128 + m * 16 + crow;
#pragma unroll
        for (int r = 0; r < 4; ++r) {
            int row = rbase + r;
            if (row < M) {
                unsigned short* Yp = Y + (size_t)row * 1024 + col0 + wc * 64 + fr16;
#pragma unroll
                for (int n = 0; n < 4; ++n)
                    Yp[n * 16] = f2bf(acc[m][n][r]);
            }
        }
    }
}

// ---------------- GEMM1 fallback (in-kernel f32->bf16, 128^2; BT already folded) --
__global__ __launch_bounds__(256) void gemm1_cvt(
    const float* __restrict__ A, int M,
    const unsigned short* __restrict__ BT,
    unsigned short* __restrict__ Y)
{
    __shared__ __align__(16) unsigned short As[128][32];
    __shared__ __align__(16) unsigned short Bs[2][128][32];

    const int t    = threadIdx.x;
    const int wid  = t >> 6;
    const int lane = t & 63;
    const int nby = (M + 127) >> 7;
    const int b   = blockIdx.x;
    const int swz = (b & 7) * nby + (b >> 3);
    const int row0 = (swz >> 3) << 7;
    const int col0 = (swz & 7) << 7;

    const int ar  = t >> 1;
    const int akq = (t & 1) << 4;
    int garow = row0 + ar; if (garow >= M) garow = M - 1;
    const float* aptr = A + (size_t)garow * GK + akq;

    const int i0 = wid * 64 + lane;
    const unsigned short* bptr0 = BT + ((size_t)(col0 + (i0 >> 2)) * KP + ((i0 & 3) << 3));
    const unsigned short* bptr1 = bptr0 + (size_t)64 * KP;

    const int wr   = wid >> 1, wc = wid & 1;
    const int fr16 = lane & 15;
    const int kb8  = (lane >> 4) << 3;

    f32x4 acc[4][4];
#pragma unroll
    for (int m = 0; m < 4; ++m)
#pragma unroll
        for (int n = 0; n < 4; ++n) acc[m][n] = (f32x4)0.0f;

    GLL16(bptr0, &Bs[0][wid * 16][0]);
    GLL16(bptr1, &Bs[0][64 + wid * 16][0]);

    float frg[16];
    {
        const float4* p = (const float4*)aptr;
        float4 v0 = p[0], v1 = p[1], v2 = p[2], v3 = p[3];
        frg[0]=v0.x; frg[1]=v0.y; frg[2]=v0.z;  frg[3]=v0.w;
        frg[4]=v1.x; frg[5]=v1.y; frg[6]=v1.z;  frg[7]=v1.w;
        frg[8]=v2.x; frg[9]=v2.y; frg[10]=v2.z; frg[11]=v2.w;
        frg[12]=v3.x;frg[13]=v3.y;frg[14]=v3.z; frg[15]=v3.w;
    }

    int cur = 0;
    for (int it = 0; it < NT1C; ++it) {
        {
            unsigned short us[16];
#pragma unroll
            for (int j = 0; j < 16; ++j) us[j] = f2bf(frg[j]);
            *(u16x8*)&As[ar][akq]     = *(u16x8*)&us[0];
            *(u16x8*)&As[ar][akq + 8] = *(u16x8*)&us[8];
        }
        __syncthreads();

        if (it + 1 < NT1C) {
            int kb = (it + 1) * 32 + akq;
            if (kb < GK) {
                const float4* p = (const float4*)(aptr + (size_t)(it + 1) * 32);
                float4 v0 = p[0], v1 = p[1], v2 = p[2], v3 = p[3];
                frg[0]=v0.x; frg[1]=v0.y; frg[2]=v0.z;  frg[3]=v0.w;
                frg[4]=v1.x; frg[5]=v1.y; frg[6]=v1.z;  frg[7]=v1.w;
                frg[8]=v2.x; frg[9]=v2.y; frg[10]=v2.z; frg[11]=v2.w;
                frg[12]=v3.x;frg[13]=v3.y;frg[14]=v3.z; frg[15]=v3.w;
            } else {
#pragma unroll
                for (int j = 0; j < 16; ++j) frg[j] = 0.0f;
            }
            const unsigned short* bp = bptr0 + (size_t)(it + 1) * 32;
            GLL16(bp,                   &Bs[cur ^ 1][wid * 16][0]);
            GLL16(bp + (size_t)64 * KP, &Bs[cur ^ 1][64 + wid * 16][0]);
        }

        bf16x8 af[4], bfr[4];
#pragma unroll
        for (int m = 0; m < 4; ++m)
            af[m] = *(const bf16x8*)&As[wr * 64 + m * 16 + fr16][kb8];
#pragma unroll
        for (int n = 0; n < 4; ++n)
            bfr[n] = *(const bf16x8*)&Bs[cur][wc * 64 + n * 16 + fr16][kb8];
#pragma unroll
        for (int m = 0; m < 4; ++m)
#pragma unroll
            for (int n = 0; n < 4; ++n)
                acc[m][n] = __builtin_amdgcn_mfma_f32_16x16x32_bf16(
                    af[m], bfr[n], acc[m][n], 0, 0, 0);

        __syncthreads();
        cur ^= 1;
    }

    const int crow = (lane >> 4) << 2;
#pragma unroll
    for (int m = 0; m < 4; ++m) {
        int rbase = row0 + wr * 64 + m * 16 + crow;
#pragma unroll
        for (int r = 0; r < 4; ++r) {
            int row = rbase + r;
            if (row < M) {
                unsigned short* Yp = Y + (size_t)row * 1024 + col0 + wc * 64 + fr16;
#pragma unroll
                for (int n = 0; n < 4; ++n)
                    Yp[n * 16] = f2bf(acc[m][n][r]);
            }
        }
    }
}

// ---------------- agg1: mean-gather(Yl) + b1' + self(Yr) + ReLU -> h (bf16) ------
// BN pre-folded into weights/bias; 2x edge unroll for MLP.
__global__ __launch_bounds__(256) void agg1_kernel(
    const unsigned short* __restrict__ Y, unsigned short* __restrict__ Hh,
    const int* __restrict__ row_start, const int* __restrict__ colidx,
    const float* __restrict__ b1p, int n)
{
    int wid  = (blockIdx.x * blockDim.x + threadIdx.x) >> 6;
    int lane = threadIdx.x & 63;
    if (wid >= n) return;
    int c0 = lane * 8;
    float bb[8];
    *(float4*)&bb[0] = *(const float4*)&b1p[c0];
    *(float4*)&bb[4] = *(const float4*)&b1p[c0 + 4];

    int s0 = row_start[wid], s1 = row_start[wid + 1];
    float acc[8] = {0, 0, 0, 0, 0, 0, 0, 0};
    int i = s0;
    for (; i + 2 <= s1; i += 2) {
        int src0 = colidx[i], src1 = colidx[i + 1];
        u16x8 v0 = *(const u16x8*)&Y[(size_t)src0 * 1024 + c0];
        u16x8 v1 = *(const u16x8*)&Y[(size_t)src1 * 1024 + c0];
#pragma unroll
        for (int j = 0; j < 8; ++j) acc[j] += bf2f(v0[j]) + bf2f(v1[j]);
    }
    if (i < s1) {
        int src = colidx[i];
        u16x8 v = *(const u16x8*)&Y[(size_t)src * 1024 + c0];
#pragma unroll
        for (int j = 0; j < 8; ++j) acc[j] += bf2f(v[j]);
    }
    float inv = 1.0f / fmaxf((float)(s1 - s0), 1.0f);
    u16x8 sv = *(const u16x8*)&Y[(size_t)wid * 1024 + 512 + c0];
    unsigned short o[8];
#pragma unroll
    for (int j = 0; j < 8; ++j) {
        float pre = acc[j] * inv + bb[j] + bf2f(sv[j]);
        o[j] = f2bf(fmaxf(pre, 0.0f));
    }
    *(u16x8*)&Hh[(size_t)wid * 512 + c0] = *(u16x8*)o;
}

// ---------------- GEMM2: U[M x 128](bf16) = h[M x 512](bf16) @ BT2^T ------------
__global__ __launch_bounds__(256) void gemm2_bf16(
    const unsigned short* __restrict__ Hh, int M,
    const unsigned short* __restrict__ BT2,
    unsigned short* __restrict__ U)
{
    __shared__ __align__(16) unsigned short As[2][128][32];
    __shared__ __align__(16) unsigned short Bs[2][128][32];

    const int t    = threadIdx.x;
    const int wid  = t >> 6;
    const int lane = t & 63;
    const int row0 = blockIdx.x << 7;

    const int c_lo = wid * 64 + lane;
    const int c_hi = c_lo + 256;
    const int s_lo = ((c_lo & 3) ^ ((c_lo >> 3) & 3)) << 3;   // src granule (elems)
    const int s_hi = ((c_hi & 3) ^ ((c_hi >> 3) & 3)) << 3;
    int ra = row0 + (c_lo >> 2); if (ra >= M) ra = M - 1;
    int rbw = row0 + (c_hi >> 2); if (rbw >= M) rbw = M - 1;
    const unsigned short* aSrc0 = Hh + (size_t)ra * 512 + s_lo;
    const unsigned short* aSrc1 = Hh + (size_t)rbw * 512 + s_hi;
    const unsigned short* bSrc0 = BT2 + (size_t)(c_lo >> 2) * 512 + s_lo;
    const unsigned short* bSrc1 = BT2 + (size_t)(c_hi >> 2) * 512 + s_hi;

    const int wr   = wid >> 1, wc = wid & 1;
    const int fr16 = lane & 15;
    const int gsw2 = ((lane >> 4) ^ ((fr16 >> 1) & 3)) << 4;  // read byte offset

    f32x4 acc[4][4];
#pragma unroll
    for (int m = 0; m < 4; ++m)
#pragma unroll
        for (int n = 0; n < 4; ++n) acc[m][n] = (f32x4)0.0f;

#define STAGE2(kt, buf) do {                                                  \
        int ko = (kt) * 32;                                                   \
        GLL16(aSrc0 + ko, (unsigned short*)&As[buf][0][0] + (size_t)c_lo * 8);  \
        GLL16(aSrc1 + ko, (unsigned short*)&As[buf][0][0] + (size_t)c_hi * 8);  \
        GLL16(bSrc0 + ko, (unsigned short*)&Bs[buf][0][0] + (size_t)c_lo * 8);  \
        GLL16(bSrc1 + ko, (unsigned short*)&Bs[buf][0][0] + (size_t)c_hi * 8);  \
    } while (0)

    STAGE2(0, 0);
    int cur = 0;
    for (int it = 0; it < NT2; ++it) {
        __syncthreads();
        if (it + 1 < NT2) STAGE2(it + 1, cur ^ 1);

        const char* Ab = (const char*)&As[cur][0][0];
        const char* Bb = (const char*)&Bs[cur][0][0];
        bf16x8 af[4], bfr[4];
#pragma unroll
        for (int m = 0; m < 4; ++m)
            af[m] = *(const bf16x8*)(Ab + ((wr * 64 + m * 16 + fr16) << 6) + gsw2);
#pragma unroll
        for (int n = 0; n < 4; ++n)
            bfr[n] = *(const bf16x8*)(Bb + ((wc * 64 + n * 16 + fr16) << 6) + gsw2);
#pragma unroll
        for (int m = 0; m < 4; ++m)
#pragma unroll
            for (int n = 0; n < 4; ++n)
                acc[m][n] = __builtin_amdgcn_mfma_f32_16x16x32_bf16(
                    af[m], bfr[n], acc[m][n], 0, 0, 0);
        cur ^= 1;
    }
#undef STAGE2

    const int crow = (lane >> 4) << 2;
#pragma unroll
    for (int m = 0; m < 4; ++m) {
        int rbase = row0 + wr * 64 + m * 16 + crow;
#pragma unroll
        for (int r = 0; r < 4; ++r) {
            int row = rbase + r;
            if (row < M) {
                unsigned short* Up = U + (size_t)row * 128 + wc * 64 + fr16;
#pragma unroll
                for (int n = 0; n < 4; ++n)
                    Up[n * 16] = f2bf(acc[m][n][r]);
            }
        }
    }
}

// ---------------- agg2: mean-gather(Ul) + b2 + self(Ur) -> out (f32) ----------------
__global__ __launch_bounds__(256) void agg2_kernel(
    const unsigned short* __restrict__ U,
    const int* __restrict__ row_start, const int* __restrict__ colidx,
    const float* __restrict__ b2, float* __restrict__ out, int n)
{
    int wid  = (blockIdx.x * blockDim.x + threadIdx.x) >> 6;
    int lane = threadIdx.x & 63;
    if (wid >= n) return;
    int s0 = row_start[wid], s1 = row_start[wid + 1];
    float acc = 0.f;
    int i = s0;
    for (; i + 2 <= s1; i += 2) {
        int src0 = colidx[i], src1 = colidx[i + 1];
        acc += bf2f(U[(size_t)src0 * 128 + lane]) + bf2f(U[(size_t)src1 * 128 + lane]);
    }
    if (i < s1) acc += bf2f(U[(size_t)colidx[i] * 128 + lane]);
    float inv = 1.0f / fmaxf((float)(s1 - s0), 1.0f);
    float z = acc * inv + b2[lane] + bf2f(U[(size_t)wid * 128 + 64 + lane]);
    out[(size_t)wid * 64 + lane] = z;
}

extern "C" void kernel_launch(void* const* d_in, const int* in_sizes, int n_in,
                              void* d_out, int out_size, void* d_ws, size_t ws_size,
                              hipStream_t stream) {
    const float* x     = (const float*)d_in[0];
    const int*   ei    = (const int*)d_in[1];
    const float* W1l   = (const float*)d_in[2];
    const float* b1    = (const float*)d_in[3];
    const float* W1r   = (const float*)d_in[4];
    const float* gamma = (const float*)d_in[5];
    const float* beta  = (const float*)d_in[6];
    const float* mean  = (const float*)d_in[7];
    const float* var   = (const float*)d_in[8];
    const float* W2l   = (const float*)d_in[9];
    const float* b2    = (const float*)d_in[10];
    const float* W2r   = (const float*)d_in[11];
    float* out = (float*)d_out;

    const int N = in_sizes[0] / 2000;   // 50000
    const int E = in_sizes[1] / 2;      // 800000
    const int nby = (N + 127) / 128;

    char* ws = (char*)d_ws;

    // Primary layout: xb | Y | BT | BT2 | b1p | cnt | row_start | colidx
    //   (Hh aliases xb after gemm1; U aliases Y after agg1)
    size_t need = (size_t)N * KP * 2 + (size_t)N * 1024 * 2
                + (size_t)1024 * KP * 2 + (size_t)128 * 512 * 2 + 2048
                + ((size_t)2 * N + 8 + (size_t)E) * 4;

    if (ws_size >= need) {
        unsigned short* xb  = (unsigned short*)ws;                 // N*2048 bf16
        unsigned short* Y   = xb + (size_t)N * KP;                 // N*1024 bf16
        unsigned short* BT  = Y + (size_t)N * 1024;                // 1024*2048 bf16
        unsigned short* BT2 = BT + (size_t)1024 * KP;              // 128*512 bf16
        float* b1p     = (float*)(BT2 + (size_t)128 * 512);        // 512 f32
        int* cnt       = (int*)(b1p + 512);
        int* row_start = cnt + N;
        int* colidx    = row_start + N + 4;                        // E
        unsigned short* Hh = xb;   // alias: xb dead after gemm1
        unsigned short* U  = Y;    // alias: Y dead after agg1

        hipMemsetAsync(cnt, 0, (size_t)N * sizeof(int), stream);

        prep_fused<<<4096, 256, 0, stream>>>(
            x, xb, W1l, W1r, gamma, beta, mean, var, b1, BT,
            W2l, W2r, BT2, b1p, ei, cnt, N, E);

        scan_kernel<<<1, 1024, 0, stream>>>(cnt, row_start, N);
        int eb = (E + 255) / 256;
        fill_kernel<<<eb, 256, 0, stream>>>(ei, E, row_start, cnt, colidx);

        int nbr = (N + 255) / 256;
        gemm1_256<<<nbr * 4, 512, 0, stream>>>(xb, N, BT, Y);
        agg1_kernel<<<(N + 3) / 4, 256, 0, stream>>>(
            Y, Hh, row_start, colidx, b1p, N);
        gemm2_bf16<<<nby, 256, 0, stream>>>(Hh, N, BT2, U);
        agg2_kernel<<<(N + 3) / 4, 256, 0, stream>>>(
            U, row_start, colidx, b2, out, N);
    } else {
        // Fallback layout (128^2 cvt GEMM1); uses fused prep minus conv via
        // prep_fused with xb==null is unsafe -> run prep_fused pieces inline:
        unsigned short* Y   = (unsigned short*)ws;                 // N*1024 bf16
        unsigned short* Hh  = Y + (size_t)N * 1024;                // N*512 bf16
        unsigned short* U   = Hh + (size_t)N * 512;                // N*128 bf16
        unsigned short* BT  = U + (size_t)N * 128;                 // 1024*2048 bf16
        unsigned short* BT2 = BT + (size_t)1024 * KP;              // 128*512 bf16
        float* b1p     = (float*)(BT2 + (size_t)128 * 512);
        int* cnt       = (int*)(b1p + 512);
        int* row_start = cnt + N;
        int* colidx    = row_start + N + 4;

        hipMemsetAsync(cnt, 0, (size_t)N * sizeof(int), stream);

        // reuse prep_fused but with conv range pointed at Y as harmless scratch?
        // No: run with xb = (unsigned short*)Y is WRONG (Y written later anyway
        // by gemm1_cvt, and conv would read x rows fine). conv writes N*2048
        // shorts = 204.8MB > Y. Instead launch prep_fused with the conv branch
        // disabled by passing N=0 for conv only is not supported -> use
        // dedicated small launches here.
        prep_fused<<<2048, 256, 0, stream>>>(   // blocks 0..2047 skip conv (N=0)
            x, (unsigned short*)Y /*unused*/, W1l, W1r, gamma, beta, mean, var,
            b1, BT, W2l, W2r, BT2, b1p, ei, cnt, 0, 0);
        // blocks 2048+ didn't run above; do BT/BT2/b1p/count via full grid:
        prep_fused<<<4096, 256, 0, stream>>>(
            x, (unsigned short*)Y, W1l, W1r, gamma, beta, mean, var,
            b1, BT, W2l, W2r, BT2, b1p, ei, cnt, 0, E);

        scan_kernel<<<1, 1024, 0, stream>>>(cnt, row_start, N);
        int eb = (E + 255) / 256;
        fill_kernel<<<eb, 256, 0, stream>>>(ei, E, row_start, cnt, colidx);

        gemm1_cvt<<<8 * nby, 256, 0, stream>>>(x, N, BT, Y);
        agg1_kernel<<<(N + 3) / 4, 256, 0, stream>>>(
            Y, Hh, row_start, colidx, b1p, N);
        gemm2_bf16<<<nby, 256, 0, stream>>>(Hh, N, BT2, U);
        agg2_kernel<<<(N + 3) / 4, 256, 0, stream>>>(
            U, row_start, colidx, b2, out, N);
    }
}